// Round 14
// baseline (132.411 us; speedup 1.0000x reference)
//
#include <hip/hip_runtime.h>

typedef _Float16 half_t;
typedef _Float16 hx8 __attribute__((ext_vector_type(8)));
typedef _Float16 hx4 __attribute__((ext_vector_type(4)));
typedef float fx4 __attribute__((ext_vector_type(4)));

#define LOG2E 1.44269504088896f
#define TAU 0.1f
#define NSPLIT 8

// ---------------- Kernel 1: fused ztrans + MLP (no W pre-transpose) ---------
__global__ __launch_bounds__(256) void mlpz_kernel(
    const float* __restrict__ Z, const float* __restrict__ W1,
    const float* __restrict__ b1, const float* __restrict__ W2,
    const float* __restrict__ b2, half_t* __restrict__ T,
    half_t* __restrict__ Zth)
{
  __shared__ float Ztile[64*132];       // 33.8 KB
  __shared__ half_t Hs[4][16*136];      // 17.4 KB
  const int tid = threadIdx.x;
  const int w = tid >> 6, lane = tid & 63;
  const int q = lane >> 4, c = lane & 15;
  const int rb = blockIdx.x*64;
  const int wrow = rb + w*16;

#pragma unroll
  for (int i=0;i<8;++i) {
    int fid = i*256 + tid;
    int r = fid >> 5, c4 = (fid & 31)*4;
    *(fx4*)(&Ztile[r*132 + c4]) = *(const fx4*)(Z + (size_t)(rb + r)*128 + c4);
  }
  __syncthreads();

  // emit Zth[d][rb..rb+63] (fp16)
  {
    const int d = tid >> 1, n0 = (tid & 1)*32;
#pragma unroll
    for (int i=0;i<4;++i) {
      hx8 hv;
#pragma unroll
      for (int u=0;u<8;++u) hv[u] = (half_t)Ztile[(n0 + i*8 + u)*132 + d];
      *(hx8*)(Zth + (size_t)d*8192 + rb + n0 + i*8) = hv;
    }
  }

  hx8 zb[4];
#pragma unroll
  for (int ks=0;ks<4;++ks) {
    fx4 a = *(const fx4*)(&Ztile[(w*16 + c)*132 + ks*32 + q*8]);
    fx4 b = *(const fx4*)(&Ztile[(w*16 + c)*132 + ks*32 + q*8 + 4]);
#pragma unroll
    for (int u=0;u<4;++u) { zb[ks][u] = (half_t)a[u]; zb[ks][4+u] = (half_t)b[u]; }
  }

  fx4 acc[8];
#pragma unroll
  for (int mt=0;mt<8;++mt) acc[mt] = (fx4){0.f,0.f,0.f,0.f};
#pragma unroll
  for (int mt=0;mt<8;++mt)
#pragma unroll
    for (int ks=0;ks<4;++ks) {
      hx8 aw;                           // A[m=mt*16+c][k=ks*32+8q+j] = W1[k][m]
#pragma unroll
      for (int j=0;j<8;++j)
        aw[j] = (half_t)W1[(size_t)(ks*32 + q*8 + j)*128 + mt*16 + c];
      acc[mt] = __builtin_amdgcn_mfma_f32_16x16x32_f16(aw, zb[ks], acc[mt], 0,0,0);
    }
#pragma unroll
  for (int mt=0;mt<8;++mt) {
    fx4 bias = *(const fx4*)(b1 + mt*16 + 4*q);
    hx4 hv;
#pragma unroll
    for (int i=0;i<4;++i) {
      float h = acc[mt][i] + bias[i];
      hv[i] = (half_t)(h > 0.f ? h : 0.f);
    }
    *(hx4*)(&Hs[w][c*136 + mt*16 + 4*q]) = hv;
  }

  hx8 hb[4];
#pragma unroll
  for (int ks=0;ks<4;++ks) hb[ks] = *(const hx8*)(&Hs[w][c*136 + ks*32 + q*8]);
#pragma unroll
  for (int mt=0;mt<8;++mt) acc[mt] = (fx4){0.f,0.f,0.f,0.f};
#pragma unroll
  for (int mt=0;mt<8;++mt)
#pragma unroll
    for (int ks=0;ks<4;++ks) {
      hx8 aw;
#pragma unroll
      for (int j=0;j<8;++j)
        aw[j] = (half_t)W2[(size_t)(ks*32 + q*8 + j)*128 + mt*16 + c];
      acc[mt] = __builtin_amdgcn_mfma_f32_16x16x32_f16(aw, hb[ks], acc[mt], 0,0,0);
    }
#pragma unroll
  for (int mt=0;mt<8;++mt) {
    fx4 bias = *(const fx4*)(b2 + mt*16 + 4*q);
    hx4 tv;
#pragma unroll
    for (int i=0;i<4;++i) tv[i] = (half_t)(acc[mt][i] + bias[i]);
    *(hx4*)(T + (size_t)(wrow + c)*128 + mt*16 + 4*q) = tv;
  }
}

// ---------------- Kernel 2: flash attention partials — ONE barrier/tile -----
// grid 512 = 64 query-blocks x 8 key-splits. DMA double-buffer, but Ps now
// lives in Zbuf[cur^1] (stale buffer): Ps is per-wave private, so the old
// sync_c (which existed only because Ps aliased Tcur, read cross-wave) is
// DELETED -> 16 barriers instead of 32, and waves decouple across phases.
// Fill ownership: each wave fills its OWN 4 T-frags + 4 Z-frags (the Z-frags
// are exactly its Ps region -> same-wave ordering covers the overwrite).
// Buffer lifecycle (all cross-wave transitions cross a barrier):
//   Zbuf[X]: az-read(t) | barrier | Ps(t+1, own region) -> own fill(end t+1)
//            | barrier | az-read(t+2).
// NO wide hoisted operand arrays (R5/R10). NEVER __launch_bounds__(256,3+).
__global__ __launch_bounds__(256,2) void flash_kernel(
    const half_t* __restrict__ T, const half_t* __restrict__ Zt,
    half_t* __restrict__ Pacc, float* __restrict__ Pm, float* __restrict__ Pl)
{
  __shared__ half_t Tbuf[2][16*512];    // 32 KB
  __shared__ half_t Zbuf[2][16*512];    // 32 KB
  const int tid = threadIdx.x;
  const int w = tid >> 6, lane = tid & 63;
  const int q = lane >> 4, c = lane & 15;
  const int bx = blockIdx.x;
  const int qb = bx >> 3, kh = bx & 7;
  const int wrow = qb*128 + w*32;
  const int sw = (c & 7) * 8;

  hx8 bq[2][4];
#pragma unroll
  for (int nt=0;nt<2;++nt)
#pragma unroll
    for (int ks=0;ks<4;++ks)
      bq[nt][ks] = *(const hx8*)(T + (size_t)(wrow + nt*16 + c)*128 + ks*32 + q*8);

  fx4 oacc[8][2];
#pragma unroll
  for (int mtd=0;mtd<8;++mtd)
#pragma unroll
    for (int nt=0;nt<2;++nt) oacc[mtd][nt] = (fx4){0.f,0.f,0.f,0.f};
  float m_run[2] = {-1e30f,-1e30f};
  float l_run[2] = {0.f,0.f};

  const int kbase = kh*1024;

  // each wave fills its own 4 T-frags (f = w*4+i) ...
  auto issue_T = [&](int kt0, int b) {
#pragma unroll
    for (int i=0;i<4;++i) {
      int f = w*4 + i, mt = f >> 2, ks = f & 3;
      const half_t* gp = T + (size_t)(kt0 + mt*16 + c)*128 + ks*32 + q*8;
      half_t* lp = &Tbuf[b][f*512 + lane*8];
      __builtin_amdgcn_global_load_lds(
          (const __attribute__((address_space(1))) void*)gp,
          (__attribute__((address_space(3))) void*)lp, 16, 0, 0);
    }
  };
  // ... and its own 4 Z-frags (f2 = w*4+i == its Ps region)
  auto issue_Z = [&](int kt0, int b) {
#pragma unroll
    for (int i=0;i<4;++i) {
      int f2 = w*4 + i, mtd = f2 >> 1, ks2 = f2 & 1;
      const half_t* gp = Zt + (size_t)(mtd*16 + c)*8192 + kt0 + ks2*32 + q*8;
      half_t* lp = &Zbuf[b][f2*512 + lane*8];
      __builtin_amdgcn_global_load_lds(
          (const __attribute__((address_space(1))) void*)gp,
          (__attribute__((address_space(3))) void*)lp, 16, 0, 0);
    }
  };

  issue_T(kbase, 0);
  issue_Z(kbase, 0);

  for (int t=0;t<16;++t) {
    const int cur = t & 1;
    __syncthreads();                    // the ONLY barrier: drains all fills,
                                        // publishes cur, retires cur^1 readers
    half_t* Tcur = Tbuf[cur];
    half_t* Zcur = Zbuf[cur];
    half_t* Psw  = &Zbuf[cur ^ 1][w*2048];   // per-wave private, stale buffer

    // ---- scores ----
    fx4 sacc[4][2];
#pragma unroll
    for (int mt=0;mt<4;++mt)
#pragma unroll
      for (int nt=0;nt<2;++nt) sacc[mt][nt] = (fx4){0.f,0.f,0.f,0.f};
#pragma unroll
    for (int ks=0;ks<4;++ks)
#pragma unroll
      for (int mt=0;mt<4;++mt) {
        hx8 ak = *(const hx8*)(&Tcur[(mt*4+ks)*512 + lane*8]);
        sacc[mt][0] = __builtin_amdgcn_mfma_f32_16x16x32_f16(ak, bq[0][ks], sacc[mt][0], 0,0,0);
        sacc[mt][1] = __builtin_amdgcn_mfma_f32_16x16x32_f16(ak, bq[1][ks], sacc[mt][1], 0,0,0);
      }
    if (t < 15) issue_T(kbase + (t+1)*64, cur ^ 1);   // Tbuf[cur^1]: no readers now

    // ---- online softmax ----
    hx4 pk[2][4];
#pragma unroll
    for (int nt=0;nt<2;++nt) {
      float mx = -1e30f;
#pragma unroll
      for (int mt=0;mt<4;++mt)
#pragma unroll
        for (int i=0;i<4;++i) mx = fmaxf(mx, sacc[mt][nt][i]);
      mx = fmaxf(mx, __shfl_xor(mx, 16, 64));
      mx = fmaxf(mx, __shfl_xor(mx, 32, 64));
      float mnew = fmaxf(m_run[nt], mx);
      float alpha = __builtin_amdgcn_exp2f((m_run[nt]-mnew)*LOG2E);
      m_run[nt] = mnew;
      float nb = mnew*LOG2E;
      float rs = 0.f;
#pragma unroll
      for (int mt=0;mt<4;++mt) {
#pragma unroll
        for (int i=0;i<4;++i) {
          float p = __builtin_amdgcn_exp2f(sacc[mt][nt][i]*LOG2E - nb);
          rs += p;
          pk[nt][mt][i] = (half_t)p;
        }
      }
      rs += __shfl_xor(rs, 16, 64);
      rs += __shfl_xor(rs, 32, 64);
      l_run[nt] = l_run[nt]*alpha + rs;
#pragma unroll
      for (int mtd=0;mtd<8;++mtd)
#pragma unroll
        for (int i=0;i<4;++i) oacc[mtd][nt][i] *= alpha;
    }

    // P^T into per-wave private region (same-wave dep only: no barrier)
#pragma unroll
    for (int nt=0;nt<2;++nt)
#pragma unroll
      for (int mt=0;mt<4;++mt)
        *(hx4*)(&Psw[(nt*16 + c)*64 + ((mt*16 + 4*q) ^ sw)]) = pk[nt][mt];

    // read all bp upfront (same-wave; compiler orders via lgkmcnt)
    hx8 bp[2][2];
#pragma unroll
    for (int ks2=0;ks2<2;++ks2) {
      bp[ks2][0] = *(const hx8*)(&Psw[(c     )*64 + ((ks2*32 + q*8) ^ sw)]);
      bp[ks2][1] = *(const hx8*)(&Psw[(16 + c)*64 + ((ks2*32 + q*8) ^ sw)]);
    }

    // ---- PV first half ----
#pragma unroll
    for (int ks2=0;ks2<2;++ks2)
#pragma unroll
      for (int mtd=0;mtd<4;++mtd) {
        hx8 az = *(const hx8*)(&Zcur[(mtd*2+ks2)*512 + lane*8]);
        oacc[mtd][0] = __builtin_amdgcn_mfma_f32_16x16x32_f16(az, bp[ks2][0], oacc[mtd][0], 0,0,0);
        oacc[mtd][1] = __builtin_amdgcn_mfma_f32_16x16x32_f16(az, bp[ks2][1], oacc[mtd][1], 0,0,0);
      }
    // bp consumed (lgkmcnt passed) -> safe to overwrite own Ps region via DMA
    if (t < 15) issue_Z(kbase + (t+1)*64, cur ^ 1);
    // ---- PV second half ----
#pragma unroll
    for (int ks2=0;ks2<2;++ks2)
#pragma unroll
      for (int mtd=4;mtd<8;++mtd) {
        hx8 az = *(const hx8*)(&Zcur[(mtd*2+ks2)*512 + lane*8]);
        oacc[mtd][0] = __builtin_amdgcn_mfma_f32_16x16x32_f16(az, bp[ks2][0], oacc[mtd][0], 0,0,0);
        oacc[mtd][1] = __builtin_amdgcn_mfma_f32_16x16x32_f16(az, bp[ks2][1], oacc[mtd][1], 0,0,0);
      }
  }

#pragma unroll
  for (int nt=0;nt<2;++nt) {
    float inv = 1.0f / l_run[nt];
    const size_t rowg = (size_t)(bx*128 + w*32 + nt*16 + c);
#pragma unroll
    for (int mtd=0;mtd<8;++mtd) {
      hx4 ov;
#pragma unroll
      for (int i=0;i<4;++i) ov[i] = (half_t)(oacc[mtd][nt][i]*inv);
      *(hx4*)(Pacc + rowg*128 + mtd*16 + 4*q) = ov;
    }
    if (q == 0) {
      Pm[rowg] = m_run[nt];
      Pl[rowg] = l_run[nt];
    }
  }
}

// ---------------- Kernel 3: merge NSPLIT key-split partials ----------------
__global__ __launch_bounds__(256) void merge_kernel(
    const float* __restrict__ Z, const half_t* __restrict__ Pacc,
    const float* __restrict__ Pm, const float* __restrict__ Pl,
    float* __restrict__ out)
{
  const int th = blockIdx.x*256 + threadIdx.x;
  const int r = th >> 5, cg = th & 31;
  const int qb = r >> 7, rr = r & 127;
  float mk[NSPLIT], lk[NSPLIT];
  float M = -1e30f;
#pragma unroll
  for (int k=0;k<NSPLIT;++k) {
    int p = qb*NSPLIT + k;
    mk[k] = Pm[p*128 + rr];
    lk[k] = Pl[p*128 + rr];
    M = fmaxf(M, mk[k]);
  }
  float L = 0.f, wk[NSPLIT];
#pragma unroll
  for (int k=0;k<NSPLIT;++k) { wk[k] = lk[k]*__builtin_amdgcn_exp2f((mk[k]-M)*LOG2E); L += wk[k]; }
  float o0=0.f,o1=0.f,o2=0.f,o3=0.f;
#pragma unroll
  for (int k=0;k<NSPLIT;++k) {
    int p = qb*NSPLIT + k;
    hx4 v = *(const hx4*)(Pacc + ((size_t)p*128 + rr)*128 + cg*4);
    o0 += wk[k]*(float)v[0]; o1 += wk[k]*(float)v[1];
    o2 += wk[k]*(float)v[2]; o3 += wk[k]*(float)v[3];
  }
  float invL = 1.0f / L;
  fx4 zv = *(const fx4*)(Z + (size_t)r*128 + cg*4);
  fx4 res;
  res[0] = (1.f-TAU)*zv[0] + TAU*o0*invL;
  res[1] = (1.f-TAU)*zv[1] + TAU*o1*invL;
  res[2] = (1.f-TAU)*zv[2] + TAU*o2*invL;
  res[3] = (1.f-TAU)*zv[3] + TAU*o3*invL;
  *(fx4*)(out + (size_t)r*128 + cg*4) = res;
}

extern "C" void kernel_launch(void* const* d_in, const int* in_sizes, int n_in,
                              void* d_out, int out_size, void* d_ws, size_t ws_size,
                              hipStream_t stream) {
  const float* Z  = (const float*)d_in[0];
  const float* W1 = (const float*)d_in[1];
  const float* b1 = (const float*)d_in[2];
  const float* W2 = (const float*)d_in[3];
  const float* b2 = (const float*)d_in[4];
  float* out = (float*)d_out;

  char* ws = (char*)d_ws;
  const size_t NBLK = 64 * NSPLIT;                                // 512
  half_t* Thi  = (half_t*)(ws);                                   // 2 MB
  half_t* Zth  = (half_t*)(ws + (size_t)2*1024*1024);             // 2 MB
  half_t* Pacc = (half_t*)(ws + (size_t)4*1024*1024);             // 16 MB
  float*  Pm   = (float*)(ws + (size_t)4*1024*1024 + NBLK*128*128*2);
  float*  Pl   = Pm + NBLK*128;

  hipLaunchKernelGGL(mlpz_kernel,  dim3(128),  dim3(256), 0, stream, Z, W1, b1, W2, b2, Thi, Zth);
  hipLaunchKernelGGL(flash_kernel, dim3(NBLK), dim3(256), 0, stream, Thi, Zth, Pacc, Pm, Pl);
  hipLaunchKernelGGL(merge_kernel, dim3(1024), dim3(256), 0, stream, Z, Pacc, Pm, Pl, out);
}

// Round 15
// 128.858 us; speedup vs baseline: 1.0276x; 1.0276x over previous
//
#include <hip/hip_runtime.h>

typedef _Float16 half_t;
typedef _Float16 hx8 __attribute__((ext_vector_type(8)));
typedef _Float16 hx4 __attribute__((ext_vector_type(4)));
typedef float fx4 __attribute__((ext_vector_type(4)));

#define LOG2E 1.44269504088896f
#define TAU 0.1f
#define NSPLIT 8

// ---------------- Kernel 1: fused ztrans + MLP, full-chip -------------------
// 256 blocks x 32 rows, 2 waves x 16 rows (was 128 blocks = half the CUs idle).
// Each block stages its 32 Z-rows (fp32) in LDS once: emits Zth (fp16 Z^T)
// AND feeds layer-1 B-frags from it. W fragments gathered straight from
// W1/W2 (A[m][k] = W[k][m]; 64B-coalesced across the 16 c-lanes, L2-hot).
__global__ __launch_bounds__(128) void mlpz_kernel(
    const float* __restrict__ Z, const float* __restrict__ W1,
    const float* __restrict__ b1, const float* __restrict__ W2,
    const float* __restrict__ b2, half_t* __restrict__ T,
    half_t* __restrict__ Zth)
{
  __shared__ float Ztile[32*132];       // 16.9 KB
  __shared__ half_t Hs[2][16*136];      // 8.7 KB
  const int tid = threadIdx.x;
  const int w = tid >> 6, lane = tid & 63;
  const int q = lane >> 4, c = lane & 15;
  const int rb = blockIdx.x*32;
  const int wrow = rb + w*16;

  // stage 32 Z-rows (1024 fx4 slots / 128 threads = 8 iters, coalesced)
#pragma unroll
  for (int i=0;i<8;++i) {
    int fid = i*128 + tid;
    int r = fid >> 5, c4 = (fid & 31)*4;
    *(fx4*)(&Ztile[r*132 + c4]) = *(const fx4*)(Z + (size_t)(rb + r)*128 + c4);
  }
  __syncthreads();

  // emit Zth[d][rb..rb+31] (fp16); thread tid owns dim d = tid
  {
    const int d = tid;
#pragma unroll
    for (int i=0;i<4;++i) {
      hx8 hv;
#pragma unroll
      for (int u=0;u<8;++u) hv[u] = (half_t)Ztile[(i*8 + u)*132 + d];
      *(hx8*)(Zth + (size_t)d*8192 + rb + i*8) = hv;
    }
  }

  // layer-1 B-frags (data rows) from the staged tile
  hx8 zb[4];
#pragma unroll
  for (int ks=0;ks<4;++ks) {
    fx4 a = *(const fx4*)(&Ztile[(w*16 + c)*132 + ks*32 + q*8]);
    fx4 b = *(const fx4*)(&Ztile[(w*16 + c)*132 + ks*32 + q*8 + 4]);
#pragma unroll
    for (int u=0;u<4;++u) { zb[ks][u] = (half_t)a[u]; zb[ks][4+u] = (half_t)b[u]; }
  }

  fx4 acc[8];
#pragma unroll
  for (int mt=0;mt<8;++mt) acc[mt] = (fx4){0.f,0.f,0.f,0.f};
#pragma unroll
  for (int mt=0;mt<8;++mt)
#pragma unroll
    for (int ks=0;ks<4;++ks) {
      hx8 aw;                           // A[m=mt*16+c][k=ks*32+8q+j] = W1[k][m]
#pragma unroll
      for (int j=0;j<8;++j)
        aw[j] = (half_t)W1[(size_t)(ks*32 + q*8 + j)*128 + mt*16 + c];
      acc[mt] = __builtin_amdgcn_mfma_f32_16x16x32_f16(aw, zb[ks], acc[mt], 0,0,0);
    }
#pragma unroll
  for (int mt=0;mt<8;++mt) {
    fx4 bias = *(const fx4*)(b1 + mt*16 + 4*q);
    hx4 hv;
#pragma unroll
    for (int i=0;i<4;++i) {
      float h = acc[mt][i] + bias[i];
      hv[i] = (half_t)(h > 0.f ? h : 0.f);
    }
    *(hx4*)(&Hs[w][c*136 + mt*16 + 4*q]) = hv;
  }

  hx8 hb[4];
#pragma unroll
  for (int ks=0;ks<4;++ks) hb[ks] = *(const hx8*)(&Hs[w][c*136 + ks*32 + q*8]);
#pragma unroll
  for (int mt=0;mt<8;++mt) acc[mt] = (fx4){0.f,0.f,0.f,0.f};
#pragma unroll
  for (int mt=0;mt<8;++mt)
#pragma unroll
    for (int ks=0;ks<4;++ks) {
      hx8 aw;
#pragma unroll
      for (int j=0;j<8;++j)
        aw[j] = (half_t)W2[(size_t)(ks*32 + q*8 + j)*128 + mt*16 + c];
      acc[mt] = __builtin_amdgcn_mfma_f32_16x16x32_f16(aw, hb[ks], acc[mt], 0,0,0);
    }
#pragma unroll
  for (int mt=0;mt<8;++mt) {
    fx4 bias = *(const fx4*)(b2 + mt*16 + 4*q);
    hx4 tv;
#pragma unroll
    for (int i=0;i<4;++i) tv[i] = (half_t)(acc[mt][i] + bias[i]);
    *(hx4*)(T + (size_t)(wrow + c)*128 + mt*16 + 4*q) = tv;
  }
}

// ---------------- Kernel 2: flash attention partials (R9/R13 best) ----------
// grid 512 = 64 query-blocks x 8 key-splits. DMA double-buffer via
// global_load_lds w16, issued after sync_c (best-measured position).
// Ps aliases the scores-dead current Tbuf (xor swizzle).
// Plateau note: six variants (2-barrier, 1-barrier, 3-barrier/32KB, explicit
// ds_write staging, early-issue DMA, hysteresis) all land 58-61 us — the
// pace-setter is the intra-wave dep chain at 2 blocks/CU, not barrier count.
// NO wide hoisted operand arrays (R5/R10). NEVER __launch_bounds__(256,3+).
__global__ __launch_bounds__(256,2) void flash_kernel(
    const half_t* __restrict__ T, const half_t* __restrict__ Zt,
    half_t* __restrict__ Pacc, float* __restrict__ Pm, float* __restrict__ Pl)
{
  __shared__ half_t Tbuf[2][16*512];    // 32 KB
  __shared__ half_t Zbuf[2][16*512];    // 32 KB
  const int tid = threadIdx.x;
  const int w = tid >> 6, lane = tid & 63;
  const int q = lane >> 4, c = lane & 15;
  const int bx = blockIdx.x;
  const int qb = bx >> 3, kh = bx & 7;
  const int wrow = qb*128 + w*32;
  const int sw = (c & 7) * 8;

  hx8 bq[2][4];
#pragma unroll
  for (int nt=0;nt<2;++nt)
#pragma unroll
    for (int ks=0;ks<4;++ks)
      bq[nt][ks] = *(const hx8*)(T + (size_t)(wrow + nt*16 + c)*128 + ks*32 + q*8);

  fx4 oacc[8][2];
#pragma unroll
  for (int mtd=0;mtd<8;++mtd)
#pragma unroll
    for (int nt=0;nt<2;++nt) oacc[mtd][nt] = (fx4){0.f,0.f,0.f,0.f};
  float m_run[2] = {-1e30f,-1e30f};
  float l_run[2] = {0.f,0.f};

  const int kbase = kh*1024;

  auto issue_loads = [&](int kt0, int b) {
    if (w < 2) {
#pragma unroll
      for (int i=0;i<8;++i) {
        int f = w*8 + i, mt = f >> 2, ks = f & 3;
        const half_t* gp = T + (size_t)(kt0 + mt*16 + c)*128 + ks*32 + q*8;
        half_t* lp = &Tbuf[b][f*512 + lane*8];
        __builtin_amdgcn_global_load_lds(
            (const __attribute__((address_space(1))) void*)gp,
            (__attribute__((address_space(3))) void*)lp, 16, 0, 0);
      }
    } else {
#pragma unroll
      for (int i=0;i<8;++i) {
        int f2 = (w-2)*8 + i, mtd = f2 >> 1, ks2 = f2 & 1;
        const half_t* gp = Zt + (size_t)(mtd*16 + c)*8192 + kt0 + ks2*32 + q*8;
        half_t* lp = &Zbuf[b][f2*512 + lane*8];
        __builtin_amdgcn_global_load_lds(
            (const __attribute__((address_space(1))) void*)gp,
            (__attribute__((address_space(3))) void*)lp, 16, 0, 0);
      }
    }
  };

  issue_loads(kbase, 0);

  for (int t=0;t<16;++t) {
    const int cur = t & 1;
    __syncthreads();                    // drains DMA fills of cur + publishes
    half_t* Tcur = Tbuf[cur];
    half_t* Zcur = Zbuf[cur];
    half_t* Psw  = &Tbuf[cur][w*2048];

    // ---- scores ----
    fx4 sacc[4][2];
#pragma unroll
    for (int mt=0;mt<4;++mt)
#pragma unroll
      for (int nt=0;nt<2;++nt) sacc[mt][nt] = (fx4){0.f,0.f,0.f,0.f};
#pragma unroll
    for (int ks=0;ks<4;++ks)
#pragma unroll
      for (int mt=0;mt<4;++mt) {
        hx8 ak = *(const hx8*)(&Tcur[(mt*4+ks)*512 + lane*8]);
        sacc[mt][0] = __builtin_amdgcn_mfma_f32_16x16x32_f16(ak, bq[0][ks], sacc[mt][0], 0,0,0);
        sacc[mt][1] = __builtin_amdgcn_mfma_f32_16x16x32_f16(ak, bq[1][ks], sacc[mt][1], 0,0,0);
      }

    // ---- online softmax ----
    hx4 pk[2][4];
#pragma unroll
    for (int nt=0;nt<2;++nt) {
      float mx = -1e30f;
#pragma unroll
      for (int mt=0;mt<4;++mt)
#pragma unroll
        for (int i=0;i<4;++i) mx = fmaxf(mx, sacc[mt][nt][i]);
      mx = fmaxf(mx, __shfl_xor(mx, 16, 64));
      mx = fmaxf(mx, __shfl_xor(mx, 32, 64));
      float mnew = fmaxf(m_run[nt], mx);
      float alpha = __builtin_amdgcn_exp2f((m_run[nt]-mnew)*LOG2E);
      m_run[nt] = mnew;
      float nb = mnew*LOG2E;
      float rs = 0.f;
#pragma unroll
      for (int mt=0;mt<4;++mt) {
#pragma unroll
        for (int i=0;i<4;++i) {
          float p = __builtin_amdgcn_exp2f(sacc[mt][nt][i]*LOG2E - nb);
          rs += p;
          pk[nt][mt][i] = (half_t)p;
        }
      }
      rs += __shfl_xor(rs, 16, 64);
      rs += __shfl_xor(rs, 32, 64);
      l_run[nt] = l_run[nt]*alpha + rs;
#pragma unroll
      for (int mtd=0;mtd<8;++mtd)
#pragma unroll
        for (int i=0;i<4;++i) oacc[mtd][nt][i] *= alpha;
    }

    __syncthreads();                    // all scores reads of Tcur done
    if (t < 15) issue_loads(kbase + (t+1)*64, cur ^ 1);

    // P^T into dead Tcur region, per-wave, xor-swizzled
#pragma unroll
    for (int nt=0;nt<2;++nt)
#pragma unroll
      for (int mt=0;mt<4;++mt)
        *(hx4*)(&Psw[(nt*16 + c)*64 + ((mt*16 + 4*q) ^ sw)]) = pk[nt][mt];

    // ---- PV ----
#pragma unroll
    for (int ks2=0;ks2<2;++ks2) {
      hx8 bp0 = *(const hx8*)(&Psw[(c     )*64 + ((ks2*32 + q*8) ^ sw)]);
      hx8 bp1 = *(const hx8*)(&Psw[(16 + c)*64 + ((ks2*32 + q*8) ^ sw)]);
#pragma unroll
      for (int mtd=0;mtd<8;++mtd) {
        hx8 az = *(const hx8*)(&Zcur[(mtd*2+ks2)*512 + lane*8]);
        oacc[mtd][0] = __builtin_amdgcn_mfma_f32_16x16x32_f16(az, bp0, oacc[mtd][0], 0,0,0);
        oacc[mtd][1] = __builtin_amdgcn_mfma_f32_16x16x32_f16(az, bp1, oacc[mtd][1], 0,0,0);
      }
    }
  }

#pragma unroll
  for (int nt=0;nt<2;++nt) {
    float inv = 1.0f / l_run[nt];
    const size_t rowg = (size_t)(bx*128 + w*32 + nt*16 + c);
#pragma unroll
    for (int mtd=0;mtd<8;++mtd) {
      hx4 ov;
#pragma unroll
      for (int i=0;i<4;++i) ov[i] = (half_t)(oacc[mtd][nt][i]*inv);
      *(hx4*)(Pacc + rowg*128 + mtd*16 + 4*q) = ov;
    }
    if (q == 0) {
      Pm[rowg] = m_run[nt];
      Pl[rowg] = l_run[nt];
    }
  }
}

// ---------------- Kernel 3: merge NSPLIT key-split partials ----------------
__global__ __launch_bounds__(256) void merge_kernel(
    const float* __restrict__ Z, const half_t* __restrict__ Pacc,
    const float* __restrict__ Pm, const float* __restrict__ Pl,
    float* __restrict__ out)
{
  const int th = blockIdx.x*256 + threadIdx.x;
  const int r = th >> 5, cg = th & 31;
  const int qb = r >> 7, rr = r & 127;
  float mk[NSPLIT], lk[NSPLIT];
  float M = -1e30f;
#pragma unroll
  for (int k=0;k<NSPLIT;++k) {
    int p = qb*NSPLIT + k;
    mk[k] = Pm[p*128 + rr];
    lk[k] = Pl[p*128 + rr];
    M = fmaxf(M, mk[k]);
  }
  float L = 0.f, wk[NSPLIT];
#pragma unroll
  for (int k=0;k<NSPLIT;++k) { wk[k] = lk[k]*__builtin_amdgcn_exp2f((mk[k]-M)*LOG2E); L += wk[k]; }
  float o0=0.f,o1=0.f,o2=0.f,o3=0.f;
#pragma unroll
  for (int k=0;k<NSPLIT;++k) {
    int p = qb*NSPLIT + k;
    hx4 v = *(const hx4*)(Pacc + ((size_t)p*128 + rr)*128 + cg*4);
    o0 += wk[k]*(float)v[0]; o1 += wk[k]*(float)v[1];
    o2 += wk[k]*(float)v[2]; o3 += wk[k]*(float)v[3];
  }
  float invL = 1.0f / L;
  fx4 zv = *(const fx4*)(Z + (size_t)r*128 + cg*4);
  fx4 res;
  res[0] = (1.f-TAU)*zv[0] + TAU*o0*invL;
  res[1] = (1.f-TAU)*zv[1] + TAU*o1*invL;
  res[2] = (1.f-TAU)*zv[2] + TAU*o2*invL;
  res[3] = (1.f-TAU)*zv[3] + TAU*o3*invL;
  *(fx4*)(out + (size_t)r*128 + cg*4) = res;
}

extern "C" void kernel_launch(void* const* d_in, const int* in_sizes, int n_in,
                              void* d_out, int out_size, void* d_ws, size_t ws_size,
                              hipStream_t stream) {
  const float* Z  = (const float*)d_in[0];
  const float* W1 = (const float*)d_in[1];
  const float* b1 = (const float*)d_in[2];
  const float* W2 = (const float*)d_in[3];
  const float* b2 = (const float*)d_in[4];
  float* out = (float*)d_out;

  char* ws = (char*)d_ws;
  const size_t NBLK = 64 * NSPLIT;                                // 512
  half_t* Thi  = (half_t*)(ws);                                   // 2 MB
  half_t* Zth  = (half_t*)(ws + (size_t)2*1024*1024);             // 2 MB
  half_t* Pacc = (half_t*)(ws + (size_t)4*1024*1024);             // 16 MB
  float*  Pm   = (float*)(ws + (size_t)4*1024*1024 + NBLK*128*128*2);
  float*  Pl   = Pm + NBLK*128;

  hipLaunchKernelGGL(mlpz_kernel,  dim3(256),  dim3(128), 0, stream, Z, W1, b1, W2, b2, Thi, Zth);
  hipLaunchKernelGGL(flash_kernel, dim3(NBLK), dim3(256), 0, stream, Thi, Zth, Pacc, Pm, Pl);
  hipLaunchKernelGGL(merge_kernel, dim3(1024), dim3(256), 0, stream, Z, Pacc, Pm, Pl, out);
}